// Round 2
// baseline (3680.614 us; speedup 1.0000x reference)
//
#include <hip/hip_runtime.h>

// GRU fused recurrent kernel, fp32, register-broadcast version.
// B=256, S=2048, I=64, H=128. One block per batch element (256 blocks).
// 384 threads = 6 waves; thread j owns gate-preactivation column j
// (r: j<128, z: 128<=j<256, n: j>=256). Weights in VGPRs (64+128 fp32).
//
// R1 was LDS-bound: 288 broadcast ds_read_b128/CU/step = ~3456 cyc.
// R2: each wave loads h with 2 per-lane ds_read_b32, broadcasts h[k] via
// v_readlane (VALU) in the unrolled dot loop. x_t read from global with a
// 1-step register prefetch. h and r/z LDS buffers are ping-ponged and
// volatile: no LDS address is read+rewritten within one barrier interval.

#define S_LEN 2048

__device__ __forceinline__ float sigm(float x) {
    x = fminf(fmaxf(x, -30.f), 30.f);
    return 1.0f / (1.0f + __expf(-x));
}
__device__ __forceinline__ float tanh_fast(float x) {
    x = fminf(fmaxf(x, -15.f), 15.f);
    float e = __expf(2.0f * x);
    return (e - 1.0f) / (e + 1.0f);
}

__global__ __launch_bounds__(384, 2) void gru_reg_kernel(
    const float* __restrict__ x,     // (256, 2048, 64)
    const float* __restrict__ Win,   // (64, 384)
    const float* __restrict__ Wh,    // (128, 384)
    const float* __restrict__ bias,  // (768,)
    float* __restrict__ out)         // (256,2048,128) then (256,128)
{
    const int b    = blockIdx.x;
    const int j    = threadIdx.x;   // 0..383
    const int lane = j & 63;

    __shared__ float h_buf[2][128];   // ping-pong hidden state
    __shared__ float rz_buf[2][256];  // ping-pong r,z gates

    volatile float* hb = &h_buf[0][0];
    volatile float* rz = &rz_buf[0][0];

    // Per-thread weight column in registers (192 VGPRs).
    float wx[64];
    float wh[128];
#pragma unroll
    for (int i = 0; i < 64; ++i) wx[i] = Win[i * 384 + j];   // coalesced
#pragma unroll
    for (int k = 0; k < 128; ++k) wh[k] = Wh[k * 384 + j];
    const float bin = bias[j];
    const float bh  = bias[384 + j];

    if (j < 128) h_buf[0][j] = 0.0f;

    const float* xb   = x   + (size_t)b * S_LEN * 64;
    float*       outb = out + (size_t)b * S_LEN * 128;

    float vx = xb[lane];   // x[b][0][lane]
    __syncthreads();       // h init (and vx irrelevant) visible

    for (int t = 0; t < S_LEN; ++t) {
        const int p = t & 1;

        // h_{t-1} into per-lane registers: 2 conflict-free ds_read_b32/wave.
        float vh0 = hb[p * 128 + lane];         // h[lane]
        float vh1 = hb[p * 128 + 64 + lane];    // h[64+lane]

        // prefetch next x_t (L2-resident; hidden behind the 384-op k-loop)
        const int tn = (t + 1 < S_LEN) ? (t + 1) : t;
        float vxn = xb[tn * 64 + lane];

        // x-part: accx = b_in[j] + sum_k x[t][k] * Win[k][j]
        const int ix = __float_as_int(vx);
        float ax0 = bin, ax1 = 0.f;
#pragma unroll
        for (int k = 0; k < 64; k += 2) {
            float b0 = __int_as_float(__builtin_amdgcn_readlane(ix, k));
            float b1 = __int_as_float(__builtin_amdgcn_readlane(ix, k + 1));
            ax0 = fmaf(b0, wx[k],     ax0);
            ax1 = fmaf(b1, wx[k + 1], ax1);
        }
        const float accx = ax0 + ax1;

        // h-part: acch = b_h[j] + sum_k h[k] * Wh[k][j]
        const int ih0 = __float_as_int(vh0);
        const int ih1 = __float_as_int(vh1);
        float ah0 = bh, ah1 = 0.f, ah2 = 0.f, ah3 = 0.f;
#pragma unroll
        for (int k = 0; k < 64; k += 2) {
            float b0 = __int_as_float(__builtin_amdgcn_readlane(ih0, k));
            float b1 = __int_as_float(__builtin_amdgcn_readlane(ih0, k + 1));
            float b2 = __int_as_float(__builtin_amdgcn_readlane(ih1, k));
            float b3 = __int_as_float(__builtin_amdgcn_readlane(ih1, k + 1));
            ah0 = fmaf(b0, wh[k],          ah0);
            ah1 = fmaf(b1, wh[k + 1],      ah1);
            ah2 = fmaf(b2, wh[64 + k],     ah2);
            ah3 = fmaf(b3, wh[64 + k + 1], ah3);
        }
        const float acch = (ah0 + ah1) + (ah2 + ah3);

        if (j < 256) {
            rz[p * 256 + j] = sigm(accx + acch);   // r (j<128) / z (j>=128)
        }
        __syncthreads();   // barrier 1: r,z visible to n-waves
        if (j >= 256) {
            const int jj = j - 256;
            float r  = rz[p * 256 + jj];
            float z  = rz[p * 256 + 128 + jj];
            float n  = tanh_fast(fmaf(r, acch, accx));
            float ho = (j < 320) ? vh0 : vh1;      // h_{t-1}[jj], own register
            float hn = fmaf(z, ho - n, n);         // (1-z)*n + z*h
            hb[(p ^ 1) * 128 + jj] = hn;           // write OTHER buffer
            outb[t * 128 + jj] = hn;               // coalesced 256B/wave
        }
        __syncthreads();   // barrier 2: new h visible for next step
        vx = vxn;
    }

    if (j < 128) {
        // final h is in h_buf[0] (last write: t=2047, p=1, wrote p^1=0)
        out[(size_t)256 * S_LEN * 128 + (size_t)b * 128 + j] = h_buf[0][j];
    }
}

extern "C" void kernel_launch(void* const* d_in, const int* in_sizes, int n_in,
                              void* d_out, int out_size, void* d_ws, size_t ws_size,
                              hipStream_t stream) {
    const float* x    = (const float*)d_in[0];
    const float* Win  = (const float*)d_in[1];
    const float* Wh   = (const float*)d_in[2];
    const float* bias = (const float*)d_in[3];
    float* out = (float*)d_out;

    gru_reg_kernel<<<256, 384, 0, stream>>>(x, Win, Wh, bias, out);
}